// Round 6
// baseline (687.094 us; speedup 1.0000x reference)
//
#include <hip/hip_runtime.h>

#define TT 20
#define HH 64
#define NPB 128    // nodes per k_rnn block
#define HST 68     // padded LDS row stride (floats)

__device__ __forceinline__ float fast_tanh(float a) {
    a = fminf(fmaxf(a, -12.0f), 12.0f);
    float e = __builtin_amdgcn_exp2f(a * 2.885390081777927f);
    return (e - 1.0f) * __builtin_amdgcn_rcpf(e + 1.0f);
}

__device__ __forceinline__ float f4get(const float4& v, int i) {
    return i == 0 ? v.x : (i == 1 ? v.y : (i == 2 ? v.z : v.w));
}

// deg histogram, padded 1 dst per 16B; 2 edges per thread via int4
__global__ void k_deg(const int* __restrict__ ei, float* __restrict__ degp, int E) {
    int i = blockIdx.x * blockDim.x + threadIdx.x;
    int e0 = 2 * i;
    if (e0 >= E) return;
    if (e0 + 1 < E) {
        int4 p = ((const int4*)ei)[i];
        atomicAdd(&degp[4 * p.y], 1.0f);
        atomicAdd(&degp[4 * p.w], 1.0f);
    } else {
        atomicAdd(&degp[4 * ei[2 * e0 + 1]], 1.0f);
    }
}

// RNN (20 steps) + epilogue: u[n] = dinv[n] * (h_n . v), dinv[n] stored.
// 256 threads, 128 nodes/block. Thread (tj=t&15, tn=t>>4) owns
// rows {tn+16r : r=0..7} x cols {4tj..4tj+3}. Per kq: 12 ds_read_b128 / 128 FMAs.
__global__ __launch_bounds__(256) void k_rnn(
    const float* __restrict__ x,
    const float* __restrict__ W_ih, const float* __restrict__ b_ih,
    const float* __restrict__ W_hh, const float* __restrict__ b_hh,
    const float* __restrict__ W_gcn, const float* __restrict__ W_fc,
    const float* __restrict__ degp,
    float* __restrict__ u, float* __restrict__ dinv, int N)
{
    __shared__ float sH[NPB * HST];    // 34816 B
    __shared__ float sWT[HH * HST];    // 17408 B
    __shared__ float sX[NPB * TT];     // 10240 B
    __shared__ float sWih[HH], sBsum[HH], sV[HH];

    const int t  = threadIdx.x;
    const int tj = t & 15;
    const int tn = t >> 4;
    const int n0 = blockIdx.x * NPB;

    // stage W_hh transposed: sWT[k][j] = W_hh[j][k]
    for (int i = t; i < HH * HH; i += 256) {
        int j = i >> 6, k = i & 63;
        sWT[k * HST + j] = W_hh[i];
    }
    for (int i = t; i < NPB * TT; i += 256) {
        int nn = i / TT, tt = i - nn * TT;
        int n = n0 + nn; if (n >= N) n = N - 1;
        sX[nn * TT + tt] = x[(size_t)n * TT + tt];
    }
    if (t < HH) {
        sWih[t]  = W_ih[t];
        sBsum[t] = b_ih[t] + b_hh[t];
        // v = W_gcn^T w_fc (folded k_prep; coalesced over t, L2-hit)
        float a = 0.0f;
#pragma unroll 8
        for (int j = 0; j < HH; ++j) a = fmaf(W_fc[j], W_gcn[j * HH + t], a);
        sV[t] = a;
    }
    for (int i = t; i < NPB * HST; i += 256) sH[i] = 0.0f;
    __syncthreads();

    float wih[4], bs[4];
#pragma unroll
    for (int c = 0; c < 4; ++c) { wih[c] = sWih[4 * tj + c]; bs[c] = sBsum[4 * tj + c]; }

    float acc[8][4];

    for (int step = 0; step < TT; ++step) {
#pragma unroll
        for (int r = 0; r < 8; ++r) {
            const float xt = sX[(tn + 16 * r) * TT + step];
#pragma unroll
            for (int c = 0; c < 4; ++c) acc[r][c] = fmaf(xt, wih[c], bs[c]);
        }
#pragma unroll 2
        for (int kq = 0; kq < HH / 4; ++kq) {
            float4 wf[4];
#pragma unroll
            for (int q = 0; q < 4; ++q)
                wf[q] = *(const float4*)&sWT[(4 * kq + q) * HST + 4 * tj];
#pragma unroll
            for (int r = 0; r < 8; ++r) {
                const float4 hf = *(const float4*)&sH[(tn + 16 * r) * HST + 4 * kq];
#pragma unroll
                for (int q = 0; q < 4; ++q) {
                    const float hv = f4get(hf, q);
                    acc[r][0] = fmaf(hv, wf[q].x, acc[r][0]);
                    acc[r][1] = fmaf(hv, wf[q].y, acc[r][1]);
                    acc[r][2] = fmaf(hv, wf[q].z, acc[r][2]);
                    acc[r][3] = fmaf(hv, wf[q].w, acc[r][3]);
                }
            }
        }
#pragma unroll
        for (int r = 0; r < 8; ++r)
#pragma unroll
            for (int c = 0; c < 4; ++c) acc[r][c] = fast_tanh(acc[r][c]);
        __syncthreads();
#pragma unroll
        for (int r = 0; r < 8; ++r) {
            float4 o; o.x = acc[r][0]; o.y = acc[r][1]; o.z = acc[r][2]; o.w = acc[r][3];
            *(float4*)&sH[(tn + 16 * r) * HST + 4 * tj] = o;
        }
        __syncthreads();
    }

    // z = h.v from registers (acc holds h); reduce across the 16 tj lanes
    float vv[4];
#pragma unroll
    for (int c = 0; c < 4; ++c) vv[c] = sV[4 * tj + c];
#pragma unroll
    for (int r = 0; r < 8; ++r) {
        float p = 0.0f;
#pragma unroll
        for (int c = 0; c < 4; ++c) p = fmaf(acc[r][c], vv[c], p);
#pragma unroll
        for (int m = 1; m < 16; m <<= 1) p += __shfl_xor(p, m, 64);
        if (tj == 0) {
            const int n = n0 + tn + 16 * r;
            if (n < N) {
                const float dd = __frsqrt_rn(degp[4 * n] + 1.0f);  // +1 self-loop
                dinv[n] = dd;
                u[n] = dd * p;
            }
        }
    }
}

// S[d] += u[s] over all edges; S padded 1 dst per 16B
__global__ void k_edge(const int* __restrict__ ei, const float* __restrict__ u,
                       float* __restrict__ Sp, int E) {
    int i = blockIdx.x * blockDim.x + threadIdx.x;
    int e0 = 2 * i;
    if (e0 >= E) return;
    if (e0 + 1 < E) {
        int4 p = ((const int4*)ei)[i];
        atomicAdd(&Sp[4 * p.y], u[p.x]);
        atomicAdd(&Sp[4 * p.w], u[p.z]);
    } else {
        atomicAdd(&Sp[4 * ei[2 * e0 + 1]], u[ei[2 * e0]]);
    }
}

// out = dinv*(S + u) + c,  c = w_fc.b_gcn + b_fc
__global__ void k_final(const float* __restrict__ dinv, const float* __restrict__ Sp,
                        const float* __restrict__ u,
                        const float* __restrict__ b_gcn, const float* __restrict__ W_fc,
                        const float* __restrict__ b_fc,
                        float* __restrict__ out, int N) {
    float c = b_fc[0];
#pragma unroll 8
    for (int j = 0; j < HH; ++j) c = fmaf(W_fc[j], b_gcn[j], c);  // uniform, s_load-backed
    int n = blockIdx.x * blockDim.x + threadIdx.x;
    if (n >= N) return;
    float d = dinv[n];
    out[n] = fmaf(d, Sp[4 * n] + u[n], c);
}

extern "C" void kernel_launch(void* const* d_in, const int* in_sizes, int n_in,
                              void* d_out, int out_size, void* d_ws, size_t ws_size,
                              hipStream_t stream)
{
    const float* x     = (const float*)d_in[0];
    const int*   ei    = (const int*)d_in[1];
    const float* W_ih  = (const float*)d_in[2];
    const float* b_ih  = (const float*)d_in[3];
    const float* W_hh  = (const float*)d_in[4];
    const float* b_hh  = (const float*)d_in[5];
    const float* W_gcn = (const float*)d_in[6];
    const float* b_gcn = (const float*)d_in[7];
    const float* W_fc  = (const float*)d_in[8];
    const float* b_fc  = (const float*)d_in[9];
    float* out = (float*)d_out;

    const int N = in_sizes[0] / TT;
    const int E = in_sizes[1] / 2;

    char* ws = (char*)d_ws;
    size_t off = 0;
    auto alloc = [&](size_t bytes) { void* p = ws + off; off += (bytes + 255) & ~(size_t)255; return p; };
    float* degp = (float*)alloc((size_t)N * 16);   // padded: dst n at [4n]
    float* Sp   = (float*)alloc((size_t)N * 16);   // padded: dst n at [4n]
    float* u    = (float*)alloc((size_t)N * 4);
    float* dinv = (float*)alloc((size_t)N * 4);

    // degp and Sp are adjacent (modulo 256B alignment both N*16 multiples) -> one memset
    hipMemsetAsync(degp, 0, (size_t)N * 32, stream);

    const int Ehalf = (E + 1) / 2;
    k_deg  <<<(Ehalf + 255) / 256, 256, 0, stream>>>(ei, degp, E);
    k_rnn  <<<(N + NPB - 1) / NPB, 256, 0, stream>>>(x, W_ih, b_ih, W_hh, b_hh,
                                                     W_gcn, W_fc, degp, u, dinv, N);
    k_edge <<<(Ehalf + 255) / 256, 256, 0, stream>>>(ei, u, Sp, E);
    k_final<<<(N + 255) / 256, 256, 0, stream>>>(dinv, Sp, u, b_gcn, W_fc, b_fc, out, N);
}

// Round 7
// 631.606 us; speedup vs baseline: 1.0879x; 1.0879x over previous
//
#include <hip/hip_runtime.h>

#define TT 20
#define HH 64
#define NPB 64     // nodes per RNN block
#define HST 68     // padded LDS row stride (floats)
#define EB  512    // edge-histogram blocks fused into k_rnn launch

__device__ __forceinline__ float fast_tanh(float a) {
    a = fminf(fmaxf(a, -12.0f), 12.0f);
    float e = __builtin_amdgcn_exp2f(a * 2.885390081777927f);
    return (e - 1.0f) * __builtin_amdgcn_rcpf(e + 1.0f);
}

__device__ __forceinline__ float f4get(const float4& v, int i) {
    return i == 0 ? v.x : (i == 1 ? v.y : (i == 2 ? v.z : v.w));
}

// Fused: blocks [0,EB) do the deg histogram (VMEM/atomic pipes) while
// blocks [EB,..) run the RNN (VALU/LDS pipes). deg is complete by kernel end.
__global__ __launch_bounds__(256) void k_fused(
    const float* __restrict__ x,
    const float* __restrict__ W_ih, const float* __restrict__ b_ih,
    const float* __restrict__ W_hh, const float* __restrict__ b_hh,
    const float* __restrict__ W_gcn, const float* __restrict__ W_fc,
    const int* __restrict__ ei,
    int* __restrict__ degi, float* __restrict__ z,
    int N, int E)
{
    __shared__ float sH[NPB * HST];    // 17408 B
    __shared__ float sWT[HH * HST];    // 17408 B
    __shared__ float sX[NPB * TT];     //  5120 B
    __shared__ float sWih[HH], sBsum[HH], sV[HH];

    const int t = threadIdx.x;

    if (blockIdx.x < EB) {
        // ---- degree histogram, 8 edges/thread-iteration, grid-stride ----
        const int4* ei4 = (const int4*)ei;
        const int G8 = (E + 7) / 8;                 // groups of 8 edges
        for (int g = blockIdx.x * 256 + t; g < G8; g += EB * 256) {
            const int base = g * 8;
            if (base + 8 <= E) {
                int4 a = ei4[g * 4 + 0];
                int4 b = ei4[g * 4 + 1];
                int4 c = ei4[g * 4 + 2];
                int4 d = ei4[g * 4 + 3];
                atomicAdd(&degi[a.y], 1); atomicAdd(&degi[a.w], 1);
                atomicAdd(&degi[b.y], 1); atomicAdd(&degi[b.w], 1);
                atomicAdd(&degi[c.y], 1); atomicAdd(&degi[c.w], 1);
                atomicAdd(&degi[d.y], 1); atomicAdd(&degi[d.w], 1);
            } else {
                for (int e = base; e < E; ++e) atomicAdd(&degi[ei[2 * e + 1]], 1);
            }
        }
        return;
    }

    // ---- RNN tile: 64 nodes, 256 threads, 4x4 register tile ----
    const int tj = t & 15;
    const int tn = t >> 4;
    const int n0 = (blockIdx.x - EB) * NPB;

    for (int i = t; i < HH * HH; i += 256) {
        int j = i >> 6, k = i & 63;
        sWT[k * HST + j] = W_hh[i];
    }
    for (int i = t; i < NPB * TT; i += 256) {
        int nn = i / TT, tt = i - nn * TT;
        int n = n0 + nn; if (n >= N) n = N - 1;
        sX[nn * TT + tt] = x[(size_t)n * TT + tt];
    }
    if (t < HH) {
        sWih[t]  = W_ih[t];
        sBsum[t] = b_ih[t] + b_hh[t];
        float a = 0.0f;
#pragma unroll 8
        for (int j = 0; j < HH; ++j) a = fmaf(W_fc[j], W_gcn[j * HH + t], a);
        sV[t] = a;                      // v = W_gcn^T w_fc
    }
    for (int i = t; i < NPB * HST; i += 256) sH[i] = 0.0f;
    __syncthreads();

    float wih[4], bs[4];
#pragma unroll
    for (int c = 0; c < 4; ++c) { wih[c] = sWih[4 * tj + c]; bs[c] = sBsum[4 * tj + c]; }

    float acc[4][4];

    for (int step = 0; step < TT; ++step) {
#pragma unroll
        for (int r = 0; r < 4; ++r) {
            const float xt = sX[(4 * tn + r) * TT + step];
#pragma unroll
            for (int c = 0; c < 4; ++c) acc[r][c] = fmaf(xt, wih[c], bs[c]);
        }
#pragma unroll 2
        for (int kq = 0; kq < HH / 4; ++kq) {
            float4 hf[4];
#pragma unroll
            for (int r = 0; r < 4; ++r)
                hf[r] = *(const float4*)&sH[(4 * tn + r) * HST + 4 * kq];
#pragma unroll
            for (int q = 0; q < 4; ++q) {
                const float4 w = *(const float4*)&sWT[(4 * kq + q) * HST + 4 * tj];
#pragma unroll
                for (int r = 0; r < 4; ++r) {
                    const float hv = f4get(hf[r], q);
                    acc[r][0] = fmaf(hv, w.x, acc[r][0]);
                    acc[r][1] = fmaf(hv, w.y, acc[r][1]);
                    acc[r][2] = fmaf(hv, w.z, acc[r][2]);
                    acc[r][3] = fmaf(hv, w.w, acc[r][3]);
                }
            }
        }
#pragma unroll
        for (int r = 0; r < 4; ++r)
#pragma unroll
            for (int c = 0; c < 4; ++c) acc[r][c] = fast_tanh(acc[r][c]);
        __syncthreads();
#pragma unroll
        for (int r = 0; r < 4; ++r) {
            float4 o; o.x = acc[r][0]; o.y = acc[r][1]; o.z = acc[r][2]; o.w = acc[r][3];
            *(float4*)&sH[(4 * tn + r) * HST + 4 * tj] = o;
        }
        __syncthreads();
    }

    // z[n] = h_n . v from registers; reduce across the 16 tj lanes
    float vv[4];
#pragma unroll
    for (int c = 0; c < 4; ++c) vv[c] = sV[4 * tj + c];
#pragma unroll
    for (int r = 0; r < 4; ++r) {
        float p = 0.0f;
#pragma unroll
        for (int c = 0; c < 4; ++c) p = fmaf(acc[r][c], vv[c], p);
#pragma unroll
        for (int m = 1; m < 16; m <<= 1) p += __shfl_xor(p, m, 64);
        if (tj == 0) {
            const int n = n0 + 4 * tn + r;
            if (n < N) z[n] = p;
        }
    }
}

// S[d] += dinv[s]*z[s]; dinv recomputed inline (breaks deg->u->edge launch chain)
__global__ __launch_bounds__(256) void k_edge(
    const int* __restrict__ ei, const int* __restrict__ degi,
    const float* __restrict__ z, float* __restrict__ S, int E)
{
    const int4* ei4 = (const int4*)ei;
    const int G8 = (E + 7) / 8;
    const int stride = gridDim.x * 256;
    for (int g = blockIdx.x * 256 + threadIdx.x; g < G8; g += stride) {
        const int base = g * 8;
        if (base + 8 <= E) {
            int4 a = ei4[g * 4 + 0];
            int4 b = ei4[g * 4 + 1];
            int4 c = ei4[g * 4 + 2];
            int4 d = ei4[g * 4 + 3];
            // batch the 16 gathers for ILP, then the 8 atomics
            float z0 = z[a.x], z1 = z[a.z], z2 = z[b.x], z3 = z[b.z];
            float z4 = z[c.x], z5 = z[c.z], z6 = z[d.x], z7 = z[d.z];
            float g0 = (float)degi[a.x], g1 = (float)degi[a.z];
            float g2 = (float)degi[b.x], g3 = (float)degi[b.z];
            float g4 = (float)degi[c.x], g5 = (float)degi[c.z];
            float g6 = (float)degi[d.x], g7 = (float)degi[d.z];
            atomicAdd(&S[a.y], z0 * __frsqrt_rn(g0 + 1.0f));
            atomicAdd(&S[a.w], z1 * __frsqrt_rn(g1 + 1.0f));
            atomicAdd(&S[b.y], z2 * __frsqrt_rn(g2 + 1.0f));
            atomicAdd(&S[b.w], z3 * __frsqrt_rn(g3 + 1.0f));
            atomicAdd(&S[c.y], z4 * __frsqrt_rn(g4 + 1.0f));
            atomicAdd(&S[c.w], z5 * __frsqrt_rn(g5 + 1.0f));
            atomicAdd(&S[d.y], z6 * __frsqrt_rn(g6 + 1.0f));
            atomicAdd(&S[d.w], z7 * __frsqrt_rn(g7 + 1.0f));
        } else {
            for (int e = base; e < E; ++e) {
                int s = ei[2 * e], dd = ei[2 * e + 1];
                atomicAdd(&S[dd], z[s] * __frsqrt_rn((float)degi[s] + 1.0f));
            }
        }
    }
}

// out = dinv*(S + dinv*z) + c,  c = w_fc.b_gcn + b_fc
__global__ void k_final(const int* __restrict__ degi, const float* __restrict__ S,
                        const float* __restrict__ z,
                        const float* __restrict__ b_gcn, const float* __restrict__ W_fc,
                        const float* __restrict__ b_fc,
                        float* __restrict__ out, int N)
{
    float c = b_fc[0];
#pragma unroll 8
    for (int j = 0; j < HH; ++j) c = fmaf(W_fc[j], b_gcn[j], c);  // uniform, s_load-backed
    int n = blockIdx.x * blockDim.x + threadIdx.x;
    if (n >= N) return;
    float d = __frsqrt_rn((float)degi[n] + 1.0f);
    out[n] = fmaf(d, S[n] + d * z[n], c);
}

extern "C" void kernel_launch(void* const* d_in, const int* in_sizes, int n_in,
                              void* d_out, int out_size, void* d_ws, size_t ws_size,
                              hipStream_t stream)
{
    const float* x     = (const float*)d_in[0];
    const int*   ei    = (const int*)d_in[1];
    const float* W_ih  = (const float*)d_in[2];
    const float* b_ih  = (const float*)d_in[3];
    const float* W_hh  = (const float*)d_in[4];
    const float* b_hh  = (const float*)d_in[5];
    const float* W_gcn = (const float*)d_in[6];
    const float* b_gcn = (const float*)d_in[7];
    const float* W_fc  = (const float*)d_in[8];
    const float* b_fc  = (const float*)d_in[9];
    float* out = (float*)d_out;

    const int N = in_sizes[0] / TT;
    const int E = in_sizes[1] / 2;

    char* ws = (char*)d_ws;
    size_t off = 0;
    auto alloc = [&](size_t bytes) { void* p = ws + off; off += (bytes + 255) & ~(size_t)255; return p; };
    int*   degi = (int*)  alloc((size_t)N * 4);
    float* S    = (float*)alloc((size_t)N * 4);
    float* z    = (float*)alloc((size_t)N * 4);

    // degi + S are adjacent in ws: single memset covers both
    size_t span = (char*)(S + N) - (char*)degi;
    hipMemsetAsync(degi, 0, span, stream);

    const int rnnBlocks = (N + NPB - 1) / NPB;
    k_fused<<<EB + rnnBlocks, 256, 0, stream>>>(x, W_ih, b_ih, W_hh, b_hh,
                                                W_gcn, W_fc, ei, degi, z, N, E);
    k_edge <<<1024, 256, 0, stream>>>(ei, degi, z, S, E);
    k_final<<<(N + 255) / 256, 256, 0, stream>>>(degi, S, z, b_gcn, W_fc, b_fc, out, N);
}

// Round 8
// 507.406 us; speedup vs baseline: 1.3541x; 1.2448x over previous
//
#include <hip/hip_runtime.h>

#define TT 20
#define HH 64
#define EB 1024        // edge-histogram blocks fused ahead of RNN blocks
#define HSTB 72        // bf16 LDS row stride (shorts): 144B = 9*16B -> b128-aligned, bank-uniform

typedef __attribute__((ext_vector_type(8))) short short8;   // 8 bf16 = 4 VGPRs (MFMA A/B frag)
typedef __attribute__((ext_vector_type(4))) float f32x4;    // MFMA C/D frag

__device__ __forceinline__ float fast_tanh(float a) {
    a = fminf(fmaxf(a, -12.0f), 12.0f);
    float e = __builtin_amdgcn_exp2f(a * 2.885390081777927f);
    return (e - 1.0f) * __builtin_amdgcn_rcpf(e + 1.0f);
}

// bf16 round-to-nearest-even via bit trick (sign-agnostic)
__device__ __forceinline__ unsigned short f2bf(float f) {
    union { float f; unsigned u; } v; v.f = f;
    unsigned r = v.u + 0x7fffu + ((v.u >> 16) & 1u);
    return (unsigned short)(r >> 16);
}
__device__ __forceinline__ float bf2f(unsigned short b) {
    union { float f; unsigned u; } v; v.u = ((unsigned)b) << 16; return v.f;
}

// v = W_gcn^T w_fc (64 floats)
__global__ __launch_bounds__(64) void k_prep(const float* __restrict__ W_gcn,
                                             const float* __restrict__ W_fc,
                                             float* __restrict__ v) {
    const int k = threadIdx.x;
    float a = 0.0f;
#pragma unroll 8
    for (int j = 0; j < HH; ++j) a = fmaf(W_fc[j], W_gcn[j * HH + k], a);
    v[k] = a;
}

// Fused: blocks [0,EB) build deg histogram; blocks [EB,..) run the MFMA RNN,
// one wave per block, 16 nodes per block, W_hh resident in B-fragments.
__global__ __launch_bounds__(64) void k_fused(
    const float* __restrict__ x,
    const float* __restrict__ W_ih, const float* __restrict__ b_ih,
    const float* __restrict__ W_hh, const float* __restrict__ b_hh,
    const float* __restrict__ v, const int* __restrict__ ei,
    int* __restrict__ degi, float* __restrict__ z,
    int N, int E)
{
    __shared__ __align__(16) unsigned short sHh[16 * HSTB];  // h hi (bf16)
    __shared__ __align__(16) unsigned short sHl[16 * HSTB];  // h lo (bf16)
    __shared__ float sX[16 * TT];

    const int t = threadIdx.x;

    if (blockIdx.x < EB) {
        // ---- degree histogram: coalesced int2 loads, fire-and-forget atomics ----
        for (int e = blockIdx.x * 64 + t; e < E; e += EB * 64) {
            int2 p = ((const int2*)ei)[e];
            atomicAdd(&degi[p.y], 1);
        }
        return;
    }

    const int n0   = (blockIdx.x - EB) * 16;
    const int nl   = t & 15;    // A-row (m) when reading; D-col (j) / B-row (n) otherwise
    const int quad = t >> 4;

    // stage x (16 nodes x 20 steps)
    for (int i = t; i < 16 * TT; i += 64) {
        int nn = i / TT, tt = i - nn * TT;
        int n = n0 + nn; if (n >= N) n = N - 1;
        sX[i] = x[(size_t)n * TT + tt];
    }
    // zero h
    for (int i = t; i < 16 * HSTB; i += 64) { sHh[i] = 0; sHl[i] = 0; }

    // preload W_hh fragments, split hi/lo bf16.
    // B-frag (ntile tt2, kchunk kc): lane holds W[j=16*tt2+nl][k=kc*32+quad*8 .. +7]
    short8 Bh[4][2], Bl[4][2];
#pragma unroll
    for (int tt2 = 0; tt2 < 4; ++tt2)
#pragma unroll
        for (int kc = 0; kc < 2; ++kc) {
            const float* wr = W_hh + (size_t)(16 * tt2 + nl) * HH + kc * 32 + quad * 8;
            float4 w0 = *(const float4*)(wr);
            float4 w1 = *(const float4*)(wr + 4);
            float wv[8] = {w0.x, w0.y, w0.z, w0.w, w1.x, w1.y, w1.z, w1.w};
            short8 hh, ll;
#pragma unroll
            for (int j = 0; j < 8; ++j) {
                unsigned short hb = f2bf(wv[j]);
                hh[j] = (short)hb;
                ll[j] = (short)f2bf(wv[j] - bf2f(hb));
            }
            Bh[tt2][kc] = hh; Bl[tt2][kc] = ll;
        }

    float wih4[4], bs4[4], vv[4];
#pragma unroll
    for (int tt2 = 0; tt2 < 4; ++tt2) {
        int n = nl + 16 * tt2;
        wih4[tt2] = W_ih[n];
        bs4[tt2]  = b_ih[n] + b_hh[n];
        vv[tt2]   = v[n];
    }
    __syncthreads();

    f32x4 C[4];

    for (int step = 0; step < TT; ++step) {
        // init: C[tt2][r] = x[m=quad*4+r]*wih[j] + bsum[j],  j = nl+16*tt2
        float xr[4];
#pragma unroll
        for (int r = 0; r < 4; ++r) xr[r] = sX[(quad * 4 + r) * TT + step];
#pragma unroll
        for (int tt2 = 0; tt2 < 4; ++tt2)
#pragma unroll
            for (int r = 0; r < 4; ++r)
                C[tt2][r] = fmaf(xr[r], wih4[tt2], bs4[tt2]);

        // h @ W^T via 3-product split-bf16 MFMA (hh*wh + hh*wl + hl*wh)
#pragma unroll
        for (int kc = 0; kc < 2; ++kc) {
            short8 Ah = *(const short8*)&sHh[nl * HSTB + kc * 32 + quad * 8];
            short8 Al = *(const short8*)&sHl[nl * HSTB + kc * 32 + quad * 8];
#pragma unroll
            for (int tt2 = 0; tt2 < 4; ++tt2) {
                C[tt2] = __builtin_amdgcn_mfma_f32_16x16x32_bf16(Ah, Bh[tt2][kc], C[tt2], 0, 0, 0);
                C[tt2] = __builtin_amdgcn_mfma_f32_16x16x32_bf16(Ah, Bl[tt2][kc], C[tt2], 0, 0, 0);
                C[tt2] = __builtin_amdgcn_mfma_f32_16x16x32_bf16(Al, Bh[tt2][kc], C[tt2], 0, 0, 0);
            }
        }
        __syncthreads();   // A-reads done before overwrite

        // tanh, split to hi/lo bf16, pack neighbor pairs, write back h
#pragma unroll
        for (int tt2 = 0; tt2 < 4; ++tt2) {
#pragma unroll
            for (int r = 0; r < 4; ++r) {
                float hv = fast_tanh(C[tt2][r]);
                C[tt2][r] = hv;   // keep fp32 h for epilogue
                unsigned short hb = f2bf(hv);
                unsigned short lb = f2bf(hv - bf2f(hb));
                unsigned pk = ((unsigned)hb << 16) | (unsigned)lb;
                unsigned pn = __shfl_xor((int)pk, 1, 64);   // neighbor col j^1
                if (!(nl & 1)) {
                    const int row = quad * 4 + r;
                    const int col = nl + 16 * tt2;          // even
                    unsigned hw = (pn & 0xffff0000u) | (pk >> 16);
                    unsigned lw = ((pn & 0xffffu) << 16) | (pk & 0xffffu);
                    *(unsigned*)&sHh[row * HSTB + col] = hw;
                    *(unsigned*)&sHl[row * HSTB + col] = lw;
                }
            }
        }
        __syncthreads();   // writes visible before next step's A-reads
    }

    // epilogue: z[node m] = sum_j h[m][j] v[j]; C holds fp32 h
#pragma unroll
    for (int r = 0; r < 4; ++r) {
        float p = 0.0f;
#pragma unroll
        for (int tt2 = 0; tt2 < 4; ++tt2) p = fmaf(C[tt2][r], vv[tt2], p);
        p += __shfl_xor(p, 1, 64);
        p += __shfl_xor(p, 2, 64);
        p += __shfl_xor(p, 4, 64);
        p += __shfl_xor(p, 8, 64);
        if (nl == 0) {
            const int n = n0 + quad * 4 + r;
            if (n < N) z[n] = p;
        }
    }
}

// w[n] = rsqrt(deg[n]+1) * z[n]
__global__ void k_w(const int* __restrict__ degi, const float* __restrict__ z,
                    float* __restrict__ w, int N) {
    int n = blockIdx.x * blockDim.x + threadIdx.x;
    if (n < N) w[n] = __frsqrt_rn((float)degi[n] + 1.0f) * z[n];
}

// S[d] += w[s] — the R2-calibrated fast shape: 1 edge/thread, coalesced int2
__global__ void k_edge(const int* __restrict__ ei, const float* __restrict__ w,
                       float* __restrict__ S, int E) {
    int e = blockIdx.x * blockDim.x + threadIdx.x;
    if (e >= E) return;
    int2 p = ((const int2*)ei)[e];
    atomicAdd(&S[p.y], w[p.x]);
}

// out = dinv*(S + dinv*z) + c,  c = w_fc.b_gcn + b_fc
__global__ void k_final(const int* __restrict__ degi, const float* __restrict__ S,
                        const float* __restrict__ z,
                        const float* __restrict__ b_gcn, const float* __restrict__ W_fc,
                        const float* __restrict__ b_fc,
                        float* __restrict__ out, int N)
{
    float c = b_fc[0];
#pragma unroll 8
    for (int j = 0; j < HH; ++j) c = fmaf(W_fc[j], b_gcn[j], c);
    int n = blockIdx.x * blockDim.x + threadIdx.x;
    if (n >= N) return;
    float d = __frsqrt_rn((float)degi[n] + 1.0f);
    out[n] = fmaf(d, S[n] + d * z[n], c);
}

extern "C" void kernel_launch(void* const* d_in, const int* in_sizes, int n_in,
                              void* d_out, int out_size, void* d_ws, size_t ws_size,
                              hipStream_t stream)
{
    const float* x     = (const float*)d_in[0];
    const int*   ei    = (const int*)d_in[1];
    const float* W_ih  = (const float*)d_in[2];
    const float* b_ih  = (const float*)d_in[3];
    const float* W_hh  = (const float*)d_in[4];
    const float* b_hh  = (const float*)d_in[5];
    const float* W_gcn = (const float*)d_in[6];
    const float* b_gcn = (const float*)d_in[7];
    const float* W_fc  = (const float*)d_in[8];
    const float* b_fc  = (const float*)d_in[9];
    float* out = (float*)d_out;

    const int N = in_sizes[0] / TT;
    const int E = in_sizes[1] / 2;

    char* ws = (char*)d_ws;
    size_t off = 0;
    auto alloc = [&](size_t bytes) { void* p = ws + off; off += (bytes + 255) & ~(size_t)255; return p; };
    int*   degi = (int*)  alloc((size_t)N * 4);
    float* S    = (float*)alloc((size_t)N * 4);
    float* z    = (float*)alloc((size_t)N * 4);
    float* w    = (float*)alloc((size_t)N * 4);
    float* v    = (float*)alloc(HH * 4);

    // degi and S are adjacent in ws: one memset zeroes both
    size_t span = (size_t)((char*)(S + N) - (char*)degi);
    hipMemsetAsync(degi, 0, span, stream);

    k_prep <<<1, 64, 0, stream>>>(W_gcn, W_fc, v);
    const int rnnBlocks = (N + 15) / 16;
    k_fused<<<EB + rnnBlocks, 64, 0, stream>>>(x, W_ih, b_ih, W_hh, b_hh,
                                               v, ei, degi, z, N, E);
    k_w    <<<(N + 255) / 256, 256, 0, stream>>>(degi, z, w, N);
    k_edge <<<(E + 255) / 256, 256, 0, stream>>>(ei, w, S, E);
    k_final<<<(N + 255) / 256, 256, 0, stream>>>(degi, S, z, b_gcn, W_fc, b_fc, out, N);
}